// Round 14
// baseline (1281.984 us; speedup 1.0000x reference)
//
#include <hip/hip_runtime.h>
#include <hip/hip_bf16.h>

using bf16 = __hip_bfloat16;
typedef __attribute__((ext_vector_type(8))) short short8v;
typedef __attribute__((ext_vector_type(4))) float floatx4;

// Problem dims
constexpr int Bc = 16, Sc = 512, INc = 512, OUTc = 256;
constexpr int Dc = 1024, Hc = 16, Lc = 6, DFFc = 2048, HIDc = 256;
constexpr float SCALEc = 0.125f; // HD^-0.5
constexpr int QKVS = 3072;       // fused qkv row stride
constexpr size_t LSLOT = 8388608; // ushorts per layer weight slot (16 MiB): qkvo|w1|w2

__device__ inline ushort f2b(float f) { // fp32 -> bf16 RNE
    union { float f; unsigned u; } v; v.f = f;
    unsigned r = (v.u + 0x7FFF + ((v.u >> 16) & 1)) >> 16;
    return (ushort)r;
}
__device__ inline float b2f(ushort b) {
    union { unsigned u; float f; } v; v.u = ((unsigned)b) << 16;
    return v.f;
}
__device__ inline float ldf(const float* p) { return *p; }
__device__ inline float ldf(const ushort* p) { return b2f(*p); }

// async global->LDS, 16 B per lane. LDS dest is wave-uniform base + lane*16 (m104).
__device__ inline void gll16(const ushort* g, ushort* l) {
    __builtin_amdgcn_global_load_lds(
        (const __attribute__((address_space(1))) unsigned int*)g,
        (__attribute__((address_space(3))) unsigned int*)l, 16, 0, 0);
}

// ---------------- block reductions (256 threads, wave64) ----------------
__device__ inline float blockSum256(float v) {
    __shared__ float tmp[4];
#pragma unroll
    for (int o = 32; o > 0; o >>= 1) v += __shfl_xor(v, o, 64);
    int w = threadIdx.x >> 6;
    __syncthreads();
    if ((threadIdx.x & 63) == 0) tmp[w] = v;
    __syncthreads();
    return tmp[0] + tmp[1] + tmp[2] + tmp[3];
}
__device__ inline float blockMax256(float v) {
    __shared__ float tmp[4];
#pragma unroll
    for (int o = 32; o > 0; o >>= 1) v = fmaxf(v, __shfl_xor(v, o, 64));
    int w = threadIdx.x >> 6;
    __syncthreads();
    if ((threadIdx.x & 63) == 0) tmp[w] = v;
    __syncthreads();
    return fmaxf(fmaxf(tmp[0], tmp[1]), fmaxf(tmp[2], tmp[3]));
}

// ---------------- mask flag: (sum(xm[0,:]) == 0) ----------------
__global__ __launch_bounds__(256) void mask_k(const float* __restrict__ xm, float* __restrict__ flag) {
    float s = xm[threadIdx.x] + xm[threadIdx.x + 256];
    s = blockSum256(s);
    if (threadIdx.x == 0) flag[0] = (s == 0.f) ? 1.f : 0.f;
}

// ---------------- x -> bf16 (same RNE as staging -> bitwise-identical downstream) -----
__global__ __launch_bounds__(256) void cvtx_k(const float* __restrict__ x, ushort* __restrict__ xb) {
    const size_t i = ((size_t)blockIdx.x * 256 + threadIdx.x) * 16;
    __align__(16) ushort o[16];
#pragma unroll
    for (int u = 0; u < 4; ++u) {
        float4 v = *(const float4*)&x[i + u * 4];
        o[u * 4 + 0] = f2b(v.x); o[u * 4 + 1] = f2b(v.y);
        o[u * 4 + 2] = f2b(v.z); o[u * 4 + 3] = f2b(v.w);
    }
    *(short8v*)&xb[i] = *(short8v*)&o[0];
    *(short8v*)&xb[i + 8] = *(short8v*)&o[8];
}

// ---------------- weight transpose + bf16 cvt: Wt[n][k] = bf16(W[k][n]*s) ----------------
__global__ __launch_bounds__(256) void transp_k(const float* __restrict__ W, ushort* __restrict__ Wt,
                                                int K, int N, float wscale) {
    __shared__ float Ls[64][65];
    const int t = threadIdx.x;
    const int n0 = blockIdx.x * 64, k0 = blockIdx.y * 64;
    const int kr = t >> 4, n4 = (t & 15) * 4;
#pragma unroll
    for (int p = 0; p < 4; ++p) {
        float4 v = *(const float4*)&W[(size_t)(k0 + kr + p * 16) * N + n0 + n4];
        Ls[kr + p * 16][n4 + 0] = v.x; Ls[kr + p * 16][n4 + 1] = v.y;
        Ls[kr + p * 16][n4 + 2] = v.z; Ls[kr + p * 16][n4 + 3] = v.w;
    }
    __syncthreads();
    const int nr = t >> 4, k4 = (t & 15) * 4;
#pragma unroll
    for (int p = 0; p < 4; ++p) {
        ushort4 o;
        o.x = f2b(Ls[k4 + 0][nr + p * 16] * wscale); o.y = f2b(Ls[k4 + 1][nr + p * 16] * wscale);
        o.z = f2b(Ls[k4 + 2][nr + p * 16] * wscale); o.w = f2b(Ls[k4 + 3][nr + p * 16] * wscale);
        *(ushort4*)&Wt[(size_t)(n0 + nr + p * 16) * K + k0 + k4] = o;
    }
}

// ---------------- batched layer-weight transpose: 256k x 64n tiles, 512 B stores ------
// Grid (512, nlayers). id decode: [0,256) DxD m=id>>6 (16n x 4k tiles); [256,384) w1
// (32n x 4k); [384,512) w2 (16n x 8k). 512 B-contiguous writes (32 lanes/row);
// accepts ~8-way LDS read conflict on the write phase (non-critical path).
__global__ __launch_bounds__(256) void transpall_k(
    const float* __restrict__ qw, const float* __restrict__ kw, const float* __restrict__ vw,
    const float* __restrict__ ow, const float* __restrict__ w1, const float* __restrict__ w2,
    ushort* __restrict__ Wt, int l0, size_t lstride)
{
    const int l = l0 + blockIdx.y;
    ushort* slot = Wt + (size_t)blockIdx.y * lstride;
    const int id = blockIdx.x;
    int m, tx, ty;
    if (id < 256)      { m = id >> 6; int r = id & 63;  tx = r & 15; ty = r >> 4; }
    else if (id < 384) { m = 4;       int r = id - 256; tx = r & 31; ty = r >> 5; }
    else               { m = 5;       int r = id - 384; tx = r & 15; ty = r >> 4; }
    const float* W; ushort* dst; int K, N; float wscale = 1.f;
    switch (m) {
        case 0: W = qw + (size_t)l * Dc * Dc; K = Dc; N = Dc; dst = slot; wscale = SCALEc; break;
        case 1: W = kw + (size_t)l * Dc * Dc; K = Dc; N = Dc; dst = slot + 1048576; break;
        case 2: W = vw + (size_t)l * Dc * Dc; K = Dc; N = Dc; dst = slot + 2097152; break;
        case 3: W = ow + (size_t)l * Dc * Dc; K = Dc; N = Dc; dst = slot + 3145728; break;
        case 4: W = w1 + (size_t)l * Dc * DFFc; K = Dc; N = DFFc; dst = slot + 4194304; break;
        default: W = w2 + (size_t)l * DFFc * Dc; K = DFFc; N = Dc; dst = slot + 6291456; break;
    }
    __shared__ float Ls[256][65];
    const int t = threadIdx.x;
    const int n0 = tx * 64, k0 = ty * 256;
    const int krb = t >> 4, n4 = (t & 15) * 4;
#pragma unroll
    for (int p = 0; p < 16; ++p) {
        const int r = krb + p * 16;
        float4 v = *(const float4*)&W[(size_t)(k0 + r) * N + n0 + n4];
        Ls[r][n4 + 0] = v.x; Ls[r][n4 + 1] = v.y;
        Ls[r][n4 + 2] = v.z; Ls[r][n4 + 3] = v.w;
    }
    __syncthreads();
#pragma unroll
    for (int p = 0; p < 8; ++p) {
        const int idx = t + 256 * p;
        const int n = idx >> 5, kc = (idx & 31) * 8;
        __align__(16) ushort tmp[8];
#pragma unroll
        for (int u = 0; u < 8; ++u) tmp[u] = f2b(Ls[kc + u][n] * wscale);
        *(short8v*)&dst[(size_t)(n0 + n) * K + k0 + kc] = *(short8v*)tmp;
    }
}

// ---------------- MFMA GEMM (128x128 tile, BK=64, 4 waves, XOR-swizzled LDS) ----------
template <int ACT, bool ADDPOS, int OMODE>
__global__ __launch_bounds__(256) void mgemm_k(
    const ushort* __restrict__ A, const ushort* __restrict__ Bt,
    const float* __restrict__ bias, const float* __restrict__ pos,
    float* __restrict__ Cf, ushort* __restrict__ Cb,
    int M, int N, int K, float scale)
{
    __shared__ __align__(16) ushort As[128 * 64];
    __shared__ __align__(16) ushort Bs[128 * 64];
    const int tid = threadIdx.x;
    const int nx = gridDim.x;
    const int nwg = nx * gridDim.y;
    int d = blockIdx.x + blockIdx.y * nx;
    if ((nwg & 7) == 0) d = (d & 7) * (nwg >> 3) + (d >> 3); // XCD swizzle, bijective
    const int m0 = (d / nx) * 128, n0 = (d % nx) * 128;
    const int lane = tid & 63, wv = tid >> 6;
    const int wm = (wv >> 1) * 64, wn = (wv & 1) * 64;
    floatx4 acc[4][4] = {};

    const int rA8 = lane >> 3, cch = lane & 7;

    for (int k0 = 0; k0 < K; k0 += 64) {
#pragma unroll
        for (int p = 0; p < 4; ++p) {
            const int r = wv * 32 + p * 8 + rA8;
            const int cs = (cch ^ (r & 7)) * 8;
            gll16(&Bt[(size_t)(n0 + r) * K + k0 + cs], &Bs[(wv * 32 + p * 8) * 64]);
            gll16(&A[(size_t)(m0 + r) * K + k0 + cs], &As[(wv * 32 + p * 8) * 64]);
        }
        __syncthreads();
#pragma unroll
        for (int s = 0; s < 2; ++s) {
            short8v af[4], bf_[4];
            const int kg = s * 32 + (lane >> 4) * 8;
#pragma unroll
            for (int f = 0; f < 4; ++f) {
                const int ra = wm + f * 16 + (lane & 15);
                af[f] = *(const short8v*)&As[ra * 64 + (kg ^ ((ra & 7) * 8))];
                const int rb = wn + f * 16 + (lane & 15);
                bf_[f] = *(const short8v*)&Bs[rb * 64 + (kg ^ ((rb & 7) * 8))];
            }
#pragma unroll
            for (int i = 0; i < 4; ++i)
#pragma unroll
                for (int j = 0; j < 4; ++j)
                    acc[i][j] = __builtin_amdgcn_mfma_f32_16x16x32_bf16(af[i], bf_[j], acc[i][j], 0, 0, 0);
        }
        __syncthreads();
    }

    const int cc = lane & 15, rr4 = (lane >> 4) * 4;
#pragma unroll
    for (int i = 0; i < 4; ++i) {
#pragma unroll
        for (int j = 0; j < 4; ++j) {
            const int col = n0 + wn + j * 16 + cc;
            const float bsv = bias[col];
#pragma unroll
            for (int q = 0; q < 4; ++q) {
                const int row = m0 + wm + i * 16 + rr4 + q;
                float v = acc[i][j][q] + bsv;
                if (ADDPOS) v += pos[(size_t)(row & (Sc - 1)) * N + col];
                v *= scale;
                if (ACT == 1) v = fmaxf(v, 0.f);
                if (OMODE == 0) Cf[(size_t)row * N + col] = v;
                else if (OMODE == 1) Cb[(size_t)row * N + col] = f2b(v);
                else { Cf[(size_t)row * N + col] = v; Cb[(size_t)row * N + col] = f2b(v); }
            }
        }
    }
}

// ---------------- 64x64-tile MFMA GEMM for small-M / grid-starved shapes ------------
template <int OMODE>
__global__ __launch_bounds__(256) void mgemm64_k(
    const ushort* __restrict__ A, const ushort* __restrict__ Bt,
    const float* __restrict__ bias,
    float* __restrict__ Cf, ushort* __restrict__ Cb,
    int M, int N, int K)
{
    __shared__ __align__(16) ushort As[64 * 64];
    __shared__ __align__(16) ushort Bs[64 * 64];
    const int tid = threadIdx.x;
    const int nx = gridDim.x;
    const int nwg = nx * gridDim.y;
    int d = blockIdx.x + blockIdx.y * nx;
    if ((nwg & 7) == 0) d = (d & 7) * (nwg >> 3) + (d >> 3); // XCD swizzle, bijective
    const int m0 = (d / nx) * 64, n0 = (d % nx) * 64;
    const int lane = tid & 63, wv = tid >> 6;
    floatx4 acc[4] = {};

    const int rA8 = lane >> 3, cch = lane & 7;

    for (int k0 = 0; k0 < K; k0 += 64) {
#pragma unroll
        for (int p = 0; p < 2; ++p) {
            const int r = wv * 16 + p * 8 + rA8;
            const int cs = (cch ^ (r & 7)) * 8;
            gll16(&A[(size_t)(m0 + r) * K + k0 + cs], &As[(wv * 16 + p * 8) * 64]);
            gll16(&Bt[(size_t)(n0 + r) * K + k0 + cs], &Bs[(wv * 16 + p * 8) * 64]);
        }
        __syncthreads();
#pragma unroll
        for (int s = 0; s < 2; ++s) {
            const int kg = s * 32 + (lane >> 4) * 8;
            const int rb = wv * 16 + (lane & 15);
            short8v bf_ = *(const short8v*)&Bs[rb * 64 + (kg ^ ((rb & 7) * 8))];
#pragma unroll
            for (int f = 0; f < 4; ++f) {
                const int ra = f * 16 + (lane & 15);
                short8v af = *(const short8v*)&As[ra * 64 + (kg ^ ((ra & 7) * 8))];
                acc[f] = __builtin_amdgcn_mfma_f32_16x16x32_bf16(af, bf_, acc[f], 0, 0, 0);
            }
        }
        __syncthreads();
    }

    const int cc = lane & 15, rr4 = (lane >> 4) * 4;
    const int col = n0 + wv * 16 + cc;
    const float bsv = bias[col];
#pragma unroll
    for (int f = 0; f < 4; ++f) {
#pragma unroll
        for (int q = 0; q < 4; ++q) {
            const int row = m0 + f * 16 + rr4 + q;
            float v = acc[f][q] + bsv;
            if (OMODE == 0) Cf[(size_t)row * N + col] = v;
            else            Cb[(size_t)row * N + col] = f2b(v);
        }
    }
}

// ---------------- 256x256 8-phase MFMA GEMM (w1: grid 256 = 1 block/CU) ----------
#define SG256(ts, g) do { \
    if ((ts) < NT) { \
        const int sb_ = (ts) & 1; \
        const int kk_ = (ts) << 6; \
        _Pragma("unroll") \
        for (int ii_ = 0; ii_ < 2; ++ii_) { \
            const int ib_ = wv * 16 + ii_ * 8; \
            if ((g) == 0 || (g) == 2) { \
                const int r0_ = (ib_ < 64 ? ib_ : ib_ + 64) + (((g) == 2) ? 64 : 0); \
                const int rr_ = r0_ + rA8; \
                gll16(A + (size_t)(m0 + rr_) * K + kk_ + ((cch ^ (rr_ & 7)) << 3), \
                      &Al[sb_][r0_ * 64]); \
            } else { \
                const int r0_ = ((ib_ >> 5) * 64) + (ib_ & 31) + (((g) == 3) ? 32 : 0); \
                const int rr_ = r0_ + rA8; \
                gll16(Bt + (size_t)(n0 + rr_) * K + kk_ + ((cch ^ (rr_ & 7)) << 3), \
                      &Bl[sb_][r0_ * 64]); \
            } \
        } \
    } } while (0)

#define LDA256(bb, fb) \
    _Pragma("unroll") for (int f_ = 0; f_ < 4; ++f_) { \
        const int ra_ = wm + ((fb) + f_) * 16 + (lane & 15); \
        const int sw_ = (ra_ & 7) * 8; \
        af[f_][0] = *(const short8v*)&Al[bb][ra_ * 64 + ((kgl) ^ sw_)]; \
        af[f_][1] = *(const short8v*)&Al[bb][ra_ * 64 + ((32 + kgl) ^ sw_)]; }

#define LDB256(bb, jb) \
    _Pragma("unroll") for (int f_ = 0; f_ < 2; ++f_) { \
        const int rb_ = wn + ((jb) + f_) * 16 + (lane & 15); \
        const int sw_ = (rb_ & 7) * 8; \
        bf_[(jb) + f_][0] = *(const short8v*)&Bl[bb][rb_ * 64 + ((kgl) ^ sw_)]; \
        bf_[(jb) + f_][1] = *(const short8v*)&Bl[bb][rb_ * 64 + ((32 + kgl) ^ sw_)]; }

#define MM256(ib, jb) \
    __builtin_amdgcn_s_setprio(1); \
    _Pragma("unroll") for (int i_ = 0; i_ < 4; ++i_) \
    _Pragma("unroll") for (int j_ = 0; j_ < 2; ++j_) \
    _Pragma("unroll") for (int s_ = 0; s_ < 2; ++s_) \
        acc[(ib) + i_][(jb) + j_] = __builtin_amdgcn_mfma_f32_16x16x32_bf16( \
            af[i_][s_], bf_[(jb) + j_][s_], acc[(ib) + i_][(jb) + j_], 0, 0, 0); \
    __builtin_amdgcn_s_setprio(0);

__global__ __launch_bounds__(512) void mgemm256_k(
    const ushort* __restrict__ A, const ushort* __restrict__ Bt,
    const float* __restrict__ bias, ushort* __restrict__ Cb,
    int M, int N, int K, int ACT)
{
    __shared__ __align__(16) ushort Al[2][256 * 64];
    __shared__ __align__(16) ushort Bl[2][256 * 64];
    const int tid = threadIdx.x;
    const int lane = tid & 63, wv = tid >> 6;
    const int nx = gridDim.x, nwg = nx * gridDim.y;
    int d = blockIdx.x + blockIdx.y * nx;
    if ((nwg & 7) == 0) d = (d & 7) * (nwg >> 3) + (d >> 3);
    const int m0 = (d / nx) * 256, n0 = (d % nx) * 256;
    const int wm = (wv >> 2) * 128, wn = (wv & 3) * 64;
    const int rA8 = lane >> 3, cch = lane & 7;
    const int kgl = (lane >> 4) * 8;
    const int NT = K >> 6;
    floatx4 acc[8][4] = {};
    short8v af[4][2], bf_[4][2];

    SG256(0, 0); SG256(0, 1); SG256(0, 2); SG256(0, 3);
    SG256(1, 0); SG256(1, 1); SG256(1, 2);
    asm volatile("s_waitcnt vmcnt(6)" ::: "memory");
    __builtin_amdgcn_s_barrier();

    for (int t = 0; t < NT; ++t) {
        const int bb = t & 1;
        LDA256(bb, 0); LDB256(bb, 0);
        SG256(t + 1, 3);
        __builtin_amdgcn_s_barrier();
        MM256(0, 0);
        __builtin_amdgcn_s_barrier();
        LDB256(bb, 2);
        SG256(t + 2, 0);
        __builtin_amdgcn_s_barrier();
        MM256(0, 2);
        __builtin_amdgcn_s_barrier();
        LDA256(bb, 4);
        SG256(t + 2, 1);
        __builtin_amdgcn_s_barrier();
        MM256(4, 0);
        __builtin_amdgcn_s_barrier();
        SG256(t + 2, 2);
        __builtin_amdgcn_s_barrier();
        MM256(4, 2);
        // drain next tile's loads BEFORE the closing barrier so every wave's reads
        // of cross-wave-staged LDS are ordered (stage-wait -> barrier -> read)
        if (t + 2 < NT) { asm volatile("s_waitcnt vmcnt(6)" ::: "memory"); }
        else            { asm volatile("s_waitcnt vmcnt(0)" ::: "memory"); }
        __builtin_amdgcn_s_barrier();
    }

    const int cc = lane & 15, rr4 = (lane >> 4) * 4;
#pragma unroll
    for (int i = 0; i < 8; ++i) {
#pragma unroll
        for (int j = 0; j < 4; ++j) {
            const int col = n0 + wn + j * 16 + cc;
            const float bsv = bias[col];
#pragma unroll
            for (int q = 0; q < 4; ++q) {
                const int row = m0 + wm + i * 16 + rr4 + q;
                float v = acc[i][j][q] + bsv;
                if (ACT) v = fmaxf(v, 0.f);
                Cb[(size_t)row * N + col] = f2b(v);
            }
        }
    }
}

// ---------------- 256x128 8-phase MFMA GEMM (w2 grid 8x32=256, proj 8x32=256) --------
// 8 waves as 4M x 2N (wave = 64x64, acc[4][4]). A: 256 rows in 2 groups matching the
// quadrant read-sets (g0 = rows {64q..64q+31}, staged Q1 for t+2; g2 = {64q+32..+63},
// staged Q3). B: 128 rows, one group, staged Q0 for t+1 into the opposite buffer.
// Counted vmcnt(4) before each tile's closing barrier.
__global__ __launch_bounds__(512) void mgemm256x128_k(
    const ushort* __restrict__ A, const ushort* __restrict__ Bt,
    const float* __restrict__ bias, const float* __restrict__ pos, int addpos,
    float* __restrict__ Cf, ushort* __restrict__ Cb, int omode,
    int M, int N, int K, int ACT)
{
    __shared__ __align__(16) ushort Al[2][256 * 64];
    __shared__ __align__(16) ushort Bl[2][128 * 64];
    const int tid = threadIdx.x;
    const int lane = tid & 63, wv = tid >> 6;
    const int nx = gridDim.x, nwg = nx * gridDim.y;
    int d = blockIdx.x + blockIdx.y * nx;
    if ((nwg & 7) == 0) d = (d & 7) * (nwg >> 3) + (d >> 3);
    const int m0 = (d / nx) * 256, n0 = (d % nx) * 128;
    const int wm = (wv >> 1) * 64, wn = (wv & 1) * 64;
    const int rA8 = lane >> 3, cch = lane & 7;
    const int kgl = (lane >> 4) * 8;
    const int NT = K >> 6;
    floatx4 acc[4][4] = {};
    short8v af[2][2], bf_[4][2];

#define SGA(ts, g) do { \
    if ((ts) < NT) { \
        const int sb_ = (ts) & 1; \
        const int kk_ = (ts) << 6; \
        _Pragma("unroll") \
        for (int ii_ = 0; ii_ < 2; ++ii_) { \
            const int r0_ = (wv >> 1) * 64 + ((g) ? 32 : 0) + (wv & 1) * 16 + ii_ * 8; \
            const int rr_ = r0_ + rA8; \
            gll16(A + (size_t)(m0 + rr_) * K + kk_ + ((cch ^ (rr_ & 7)) << 3), \
                  &Al[sb_][r0_ * 64]); \
        } \
    } } while (0)
#define SGB(ts) do { \
    if ((ts) < NT) { \
        const int sb_ = (ts) & 1; \
        const int kk_ = (ts) << 6; \
        _Pragma("unroll") \
        for (int ii_ = 0; ii_ < 2; ++ii_) { \
            const int r0_ = wv * 16 + ii_ * 8; \
            const int rr_ = r0_ + rA8; \
            gll16(Bt + (size_t)(n0 + rr_) * K + kk_ + ((cch ^ (rr_ & 7)) << 3), \
                  &Bl[sb_][r0_ * 64]); \
        } \
    } } while (0)
#define LDAX(bb, fb) \
    _Pragma("unroll") for (int f_ = 0; f_ < 2; ++f_) { \
        const int ra_ = wm + ((fb) + f_) * 16 + (lane & 15); \
        const int sw_ = (ra_ & 7) * 8; \
        af[f_][0] = *(const short8v*)&Al[bb][ra_ * 64 + ((kgl) ^ sw_)]; \
        af[f_][1] = *(const short8v*)&Al[bb][ra_ * 64 + ((32 + kgl) ^ sw_)]; }
#define LDBX(bb, jb) \
    _Pragma("unroll") for (int f_ = 0; f_ < 2; ++f_) { \
        const int rb_ = wn + ((jb) + f_) * 16 + (lane & 15); \
        const int sw_ = (rb_ & 7) * 8; \
        bf_[(jb) + f_][0] = *(const short8v*)&Bl[bb][rb_ * 64 + ((kgl) ^ sw_)]; \
        bf_[(jb) + f_][1] = *(const short8v*)&Bl[bb][rb_ * 64 + ((32 + kgl) ^ sw_)]; }
#define MMX(ia, jb) \
    __builtin_amdgcn_s_setprio(1); \
    _Pragma("unroll") for (int i_ = 0; i_ < 2; ++i_) \
    _Pragma("unroll") for (int j_ = 0; j_ < 2; ++j_) \
    _Pragma("unroll") for (int s_ = 0; s_ < 2; ++s_) \
        acc[(ia) + i_][(jb) + j_] = __builtin_amdgcn_mfma_f32_16x16x32_bf16( \
            af[i_][s_], bf_[(jb) + j_][s_], acc[(ia) + i_][(jb) + j_], 0, 0, 0); \
    __builtin_amdgcn_s_setprio(0);

    SGA(0, 0); SGA(0, 1); SGB(0);
    SGA(1, 0); SGA(1, 1);
    asm volatile("s_waitcnt vmcnt(4)" ::: "memory");
    __builtin_amdgcn_s_barrier();

    for (int t = 0; t < NT; ++t) {
        const int bb = t & 1;
        // Q0: rows 0-1 x cols 0-1
        LDAX(bb, 0); LDBX(bb, 0);
        SGB(t + 1);
        __builtin_amdgcn_s_barrier();
        MMX(0, 0);
        __builtin_amdgcn_s_barrier();
        // Q1: rows 0-1 x cols 2-3
        LDBX(bb, 2);
        SGA(t + 2, 0);
        __builtin_amdgcn_s_barrier();
        MMX(0, 2);
        __builtin_amdgcn_s_barrier();
        // Q2: rows 2-3 x cols 0-1
        LDAX(bb, 2);
        __builtin_amdgcn_s_barrier();
        MMX(2, 0);
        __builtin_amdgcn_s_barrier();
        // Q3: rows 2-3 x cols 2-3
        SGA(t + 2, 1);
        __builtin_amdgcn_s_barrier();
        MMX(2, 2);
        if (t + 2 < NT) { asm volatile("s_waitcnt vmcnt(4)" ::: "memory"); }
        else            { asm volatile("s_waitcnt vmcnt(0)" ::: "memory"); }
        __builtin_amdgcn_s_barrier();
    }

    const int cc = lane & 15, rr4 = (lane >> 4) * 4;
#pragma unroll
    for (int i = 0; i < 4; ++i) {
#pragma unroll
        for (int j = 0; j < 4; ++j) {
            const int col = n0 + wn + j * 16 + cc;
            const float bsv = bias[col];
#pragma unroll
            for (int q = 0; q < 4; ++q) {
                const int row = m0 + wm + i * 16 + rr4 + q;
                float v = acc[i][j][q] + bsv;
                if (addpos) v += pos[(size_t)(row & (Sc - 1)) * N + col];
                if (ACT) v = fmaxf(v, 0.f);
                if (omode == 0) Cf[(size_t)row * N + col] = v;
                else            Cb[(size_t)row * N + col] = f2b(v);
            }
        }
    }
#undef SGA
#undef SGB
#undef LDAX
#undef LDBX
#undef MMX
}

// ---------------- fused attention (batch 0, bf16 qkv) ----------------
__global__ __launch_bounds__(256) void fattn_k(
    const ushort* __restrict__ qkv, ushort* __restrict__ ao, const float* __restrict__ flag)
{
    const int hh = blockIdx.y;
    const int t0 = blockIdx.x * 16;
    __shared__ __align__(16) ushort Qs[16 * 64];
    __shared__ __align__(16) ushort Ks[64 * 64];
    __shared__ float Vs[64][68];
    __shared__ float Ps[16][68];
    __shared__ float rs[4][16];
    const int tid = threadIdx.x;
    const int lane = tid & 63, wv = tid >> 6;
    const bool msk = flag[0] > 0.5f;

    if (tid < 128) {
        const int r = tid >> 3, c = tid & 7;
        short8v q = *(const short8v*)&qkv[(size_t)(t0 + r) * QKVS + hh * 64 + c * 8];
        *(short8v*)&Qs[r * 64 + ((c * 8) ^ ((r & 7) * 8))] = q;
    }
    if (tid < 64) ((float*)rs)[tid] = 0.f;

    float o[4] = {};
    const int pq = tid >> 4, pd = (tid & 15) * 4;

    for (int s0 = 0; s0 < Sc; s0 += 64) {
        __syncthreads();
        {
            const int vr = tid >> 2, vc = (tid & 3) * 16;
            const ushort* vsrc = &qkv[(size_t)(s0 + vr) * QKVS + 2048 + hh * 64 + vc];
            short8v v0 = *(const short8v*)vsrc, v1 = *(const short8v*)(vsrc + 8);
#pragma unroll
            for (int u = 0; u < 8; ++u) {
                Vs[vr][vc + u] = b2f((ushort)v0[u]);
                Vs[vr][vc + 8 + u] = b2f((ushort)v1[u]);
            }
#pragma unroll
            for (int u = 0; u < 2; ++u) {
                const int task = tid + u * 256;
                const int kr = task >> 3, kc = task & 7;
                short8v kvv = *(const short8v*)&qkv[(size_t)(s0 + kr) * QKVS + 1024 + hh * 64 + kc * 8];
                *(short8v*)&Ks[kr * 64 + ((kc * 8) ^ ((kr & 7) * 8))] = kvv;
            }
        }
        __syncthreads();
        floatx4 pacc = {};
#pragma unroll
        for (int s = 0; s < 2; ++s) {
            const int kg = s * 32 + (lane >> 4) * 8;
            const int ra = lane & 15;
            short8v aq = *(const short8v*)&Qs[ra * 64 + (kg ^ ((ra & 7) * 8))];
            const int rb = 16 * wv + (lane & 15);
            short8v bk = *(const short8v*)&Ks[rb * 64 + (kg ^ ((rb & 7) * 8))];
            pacc = __builtin_amdgcn_mfma_f32_16x16x32_bf16(aq, bk, pacc, 0, 0, 0);
        }
        const int cc = lane & 15, rr4 = (lane >> 4) * 4;
#pragma unroll
        for (int q = 0; q < 4; ++q) {
            float v = fminf(fmaxf(pacc[q], -10.f), 10.f);
            if (msk) v = -10.f;
            float e = __expf(v - 10.f);
            Ps[rr4 + q][wv * 16 + cc] = e;
            float rsum = e;
            rsum += __shfl_xor(rsum, 1, 64);
            rsum += __shfl_xor(rsum, 2, 64);
            rsum += __shfl_xor(rsum, 4, 64);
            rsum += __shfl_xor(rsum, 8, 64);
            if (cc == 0) rs[wv][rr4 + q] += rsum;
        }
        __syncthreads();
#pragma unroll 8
        for (int ss = 0; ss < 64; ++ss) {
            float p = Ps[pq][ss];
#pragma unroll
            for (int u = 0; u < 4; ++u) o[u] += p * Vs[ss][pd + u];
        }
    }
    __syncthreads();
    float inv = 1.f / (rs[0][pq] + rs[1][pq] + rs[2][pq] + rs[3][pq]);
#pragma unroll
    for (int u = 0; u < 4; ++u)
        ao[(size_t)(t0 + pq) * Dc + hh * 64 + pd + u] = f2b(o[u] * inv);
}

// ---------------- fp32 VALU GEMM (head composition): C = A@W ----------------
template <int ACT, bool OUT_BF16, bool HASB>
__global__ __launch_bounds__(256) void gemm_k(
    const float* __restrict__ A, const float* __restrict__ W,
    const float* __restrict__ bias,
    float* __restrict__ Cf, bf16* __restrict__ Cb,
    int M, int N, int K, float scale)
{
    __shared__ float As[16][68];
    __shared__ float Ws[16][68];
    const int tid = threadIdx.x;
    const int m0 = blockIdx.y * 64, n0 = blockIdx.x * 64;
    const int ty = tid >> 4, tx = tid & 15;
    float c[4][4] = {};

    const int ka = tid & 15, mb = tid >> 4;
    const int nw = tid & 63, kb = tid >> 6;

    for (int k0 = 0; k0 < K; k0 += 16) {
#pragma unroll
        for (int j = 0; j < 4; ++j) {
            int m = mb + 16 * j;
            As[ka][m] = A[(size_t)(m0 + m) * K + k0 + ka];
        }
#pragma unroll
        for (int j = 0; j < 4; ++j) {
            int k = kb + 4 * j;
            Ws[k][nw] = W[(size_t)(k0 + k) * N + n0 + nw];
        }
        __syncthreads();
#pragma unroll
        for (int k = 0; k < 16; ++k) {
            float4 av = *(const float4*)&As[k][ty * 4];
            float4 wv = *(const float4*)&Ws[k][tx * 4];
            float a[4] = {av.x, av.y, av.z, av.w};
            float w[4] = {wv.x, wv.y, wv.z, wv.w};
#pragma unroll
            for (int i = 0; i < 4; ++i)
#pragma unroll
                for (int j = 0; j < 4; ++j) c[i][j] += a[i] * w[j];
        }
        __syncthreads();
    }

#pragma unroll
    for (int i = 0; i < 4; ++i) {
        int m = m0 + ty * 4 + i;
#pragma unroll
        for (int j = 0; j < 4; ++j) {
            int n = n0 + tx * 4 + j;
            float v = c[i][j] + (HASB ? bias[n] : 0.f);
            v *= scale;
            if (ACT == 1) v = fmaxf(v, 0.f);
            if (OUT_BF16) Cb[(size_t)m * N + n] = __float2bfloat16(v);
            else          Cf[(size_t)m * N + n] = v;
        }
    }
}

// ---------------- fused head bias chain ----------------
__global__ __launch_bounds__(256) void biaschain_k(
    const float* __restrict__ fc1b, const float* __restrict__ fc2w, const float* __restrict__ fc2b,
    const float* __restrict__ fc3w, const float* __restrict__ fc3b, float* __restrict__ bc)
{
    __shared__ float vs[256];
    const int t = threadIdx.x;
    float v = fc1b[t];
    for (int r = 0; r < 5; ++r) {
        vs[t] = v; __syncthreads();
        float s = fc2b[t];
#pragma unroll 8
        for (int k = 0; k < 256; ++k) s += vs[k] * fc2w[k * 256 + t];
        v = s; __syncthreads();
    }
    vs[t] = v; __syncthreads();
    float s = fc3b[t];
#pragma unroll 8
    for (int k = 0; k < 256; ++k) s += vs[k] * fc3w[k * 256 + t];
    bc[t] = s;
}

// ---------------- qkv bias concat for ALL layers (q-part pre-scaled) ----------------
__global__ __launch_bounds__(256) void qkvbiasall_k(
    const float* __restrict__ qb, const float* __restrict__ kb, const float* __restrict__ vb,
    float* __restrict__ o)
{
    int i = blockIdx.x * 256 + threadIdx.x; // grid 72 -> 6*3072
    int l = i / QKVS, j = i - l * QKVS;
    float v = (j < 1024) ? qb[l * Dc + j] * SCALEc
            : (j < 2048) ? kb[l * Dc + j - 1024] : vb[l * Dc + j - 2048];
    o[i] = v;
}

// ---------------- fused: hb = LN(hb + softmax(clip(obv_row))) (bcast over batch) ------
__global__ __launch_bounds__(256) void smaddln_k(
    ushort* __restrict__ hb, const float* __restrict__ obv,
    const float* __restrict__ g, const float* __restrict__ b)
{
    const int row = blockIdx.x;
    const float* op = obv + (size_t)(row & (Sc - 1)) * Dc;
    ushort* hp = hb + (size_t)row * Dc;
    const int c0 = threadIdx.x * 4;
    float4 ov = *(const float4*)&op[c0];
    float r[4] = {ov.x, ov.y, ov.z, ov.w};
    float mx = -1e30f;
#pragma unroll
    for (int j = 0; j < 4; ++j) { r[j] = fminf(fmaxf(r[j], -10.f), 10.f); mx = fmaxf(mx, r[j]); }
    mx = blockMax256(mx);
    float s = 0.f;
#pragma unroll
    for (int j = 0; j < 4; ++j) { r[j] = __expf(r[j] - mx); s += r[j]; }
    s = blockSum256(s);
    float sinv = 1.f / s;
    ushort4 hv = *(const ushort4*)&hp[c0];
    float x[4] = {b2f(hv.x), b2f(hv.y), b2f(hv.z), b2f(hv.w)};
    float ssum = 0.f;
#pragma unroll
    for (int j = 0; j < 4; ++j) { x[j] += r[j] * sinv; ssum += x[j]; }
    float mean = blockSum256(ssum) * (1.f / (float)Dc);
    float vsum = 0.f;
#pragma unroll
    for (int j = 0; j < 4; ++j) { float d_ = x[j] - mean; vsum += d_ * d_; }
    float var = blockSum256(vsum) * (1.f / (float)Dc);
    float inv = rsqrtf(var + 1e-5f);
    float4 gv = *(const float4*)&g[c0];
    float4 bv = *(const float4*)&b[c0];
    ushort4 o4;
    o4.x = f2b((x[0] - mean) * inv * gv.x + bv.x);
    o4.y = f2b((x[1] - mean) * inv * gv.y + bv.y);
    o4.z = f2b((x[2] - mean) * inv * gv.z + bv.z);
    o4.w = f2b((x[3] - mean) * inv * gv.w + bv.w);
    *(ushort4*)&hp[c0] = o4;
}

// ---------------- hb = bf16(LN(hb + add)) ----------------
__global__ __launch_bounds__(256) void add_ln_k(
    ushort* __restrict__ hb, const ushort* __restrict__ add,
    const float* __restrict__ g, const float* __restrict__ b)
{
    const int row = blockIdx.x;
    const ushort* ap = add + (size_t)row * Dc;
    ushort* hp = hb + (size_t)row * Dc;
    const int c0 = threadIdx.x * 4;
    ushort4 hv = *(const ushort4*)&hp[c0];
    float x[4] = {b2f(hv.x), b2f(hv.y), b2f(hv.z), b2f(hv.w)};
#pragma unroll
    for (int j = 0; j < 4; ++j) x[j] += ldf(&ap[c0 + j]);
    float s = x[0] + x[1] + x[2] + x[3];
    float mean = blockSum256(s) * (1.f / (float)Dc);
    float vsum = 0.f;
#pragma unroll
    for (int j = 0; j < 4; ++j) { float d = x[j] - mean; vsum += d * d; }
    float var = blockSum256(vsum) * (1.f / (float)Dc);
    float inv = rsqrtf(var + 1e-5f);
    float4 gv = *(const float4*)&g[c0];
    float4 bv = *(const float4*)&b[c0];
    ushort4 ov;
    ov.x = f2b((x[0] - mean) * inv * gv.x + bv.x);
    ov.y = f2b((x[1] - mean) * inv * gv.y + bv.y);
    ov.z = f2b((x[2] - mean) * inv * gv.z + bv.z);
    ov.w = f2b((x[3] - mean) * inv * gv.w + bv.w);
    *(ushort4*)&hp[c0] = ov;
}

// ---------------- launch ----------------
extern "C" void kernel_launch(void* const* d_in, const int* in_sizes, int n_in,
                              void* d_out, int out_size, void* d_ws, size_t ws_size,
                              hipStream_t stream)
{
    const float* x      = (const float*)d_in[0];
    const float* xm     = (const float*)d_in[1];
    // d_in[2] vecSelector: assert-only, unused
    const float* proj_w = (const float*)d_in[3];
    const float* proj_b = (const float*)d_in[4];
    const float* pos    = (const float*)d_in[5];
    const float* qw     = (const float*)d_in[6];
    const float* qb     = (const float*)d_in[7];
    const float* kw     = (const float*)d_in[8];
    const float* kb     = (const float*)d_in[9];
    const float* vw     = (const float*)d_in[10];
    const float* vb     = (const float*)d_in[11];
    const float* ow     = (const float*)d_in[12];
    const float* obias  = (const float*)d_in[13];
    const float* ln1g   = (const float*)d_in[14];
    const float* ln1b   = (const float*)d_in[15];
    const float* ln2g   = (const float*)d_in[16];
    const float* ln2b   = (const float*)d_in[17];
    const float* w1     = (const float*)d_in[18];
    const float* b1     = (const float*)d_in[19];
    const float* w2     = (const float*)d_in[20];
    const float* b2     = (const float*)d_in[21];
    const float* fc1w   = (const float*)d_in[22];
    const float* fc1b   = (const float*)d_in[23];
    const float* fc2w   = (const float*)d_in[24];
    const float* fc2b   = (const float*)d_in[25];
    const float* fc3w   = (const float*)d_in[26];
    const float* fc3b   = (const float*)d_in[27];

    float* ws = (float*)d_ws;
    const size_t HSZ = (size_t)Bc * Sc * Dc; // 8,388,608 floats
    ushort* hb  = (ushort*)ws;
    ushort* ffu = (ushort*)(ws + HSZ / 2);
    float*  rgA = ws + HSZ;
    float*  meta = ws + 2 * HSZ;
    float*  flag = meta;
    float*  qkvball = meta + 256;
    ushort* Wt = (ushort*)(ws + 2 * HSZ + 262144);

    const bool big = ws_size >= (size_t)163 * 1024 * 1024;
    const size_t lstride = big ? LSLOT : 0;
    ushort* projWt = big ? Wt + (size_t)6 * LSLOT : Wt;

    ushort* qkvfu = (ushort*)rgA;
    ushort* aovu  = (ushort*)(rgA + 786432);
    float*  obv   = rgA + 1048576;
    ushort* midu  = (ushort*)rgA;
    ushort* xb    = (ushort*)rgA;  // proj phase only (dead before layer 0's attn temps)
    float* W2  = rgA;
    float* W4  = rgA + 65536;
    float* W5  = rgA + 131072;
    float* C1  = rgA + 196608;
    float* Wc  = rgA + 458752;
    float* bcv = rgA + 720896;

    const int MR = Bc * Sc; // 8192

    mask_k<<<1, 256, 0, stream>>>(xm, flag);
    qkvbiasall_k<<<72, 256, 0, stream>>>(qb, kb, vb, qkvball);
    if (big)
        transpall_k<<<dim3(512, 6), 256, 0, stream>>>(qw, kw, vw, ow, w1, w2, Wt, 0, lstride);

    // hb = bf16(x @ proj_w + proj_b + pos): 256x128 8-phase (grid 8x32 = 256)
    cvtx_k<<<(MR * INc) / (256 * 16), 256, 0, stream>>>(x, xb);
    transp_k<<<dim3(Dc / 64, INc / 64), 256, 0, stream>>>(proj_w, projWt, INc, Dc, 1.f);
    mgemm256x128_k<<<dim3(Dc / 128, MR / 256), 512, 0, stream>>>(
        xb, projWt, proj_b, pos, 1, nullptr, hb, 1, MR, Dc, INc, 0);

    for (int l = 0; l < Lc; ++l) {
        ushort* slot = Wt + (size_t)(big ? l : 0) * LSLOT;
        const float* ob_l = obias + l * Dc;
        const float* b1_l = b1 + l * DFFc;
        const float* b2_l = b2 + l * Dc;

        if (!big)
            transpall_k<<<dim3(512, 1), 256, 0, stream>>>(qw, kw, vw, ow, w1, w2, Wt, l, 0);

        // attention: batch 0 only (sa = ao[0] is all that survives)
        mgemm64_k<1><<<dim3(QKVS / 64, Sc / 64), 256, 0, stream>>>(
            hb, slot, qkvball + l * QKVS, nullptr, qkvfu, Sc, QKVS, Dc);
        fattn_k<<<dim3(Sc / 16, Hc), 256, 0, stream>>>(qkvfu, aovu, flag);
        mgemm64_k<0><<<dim3(Dc / 64, Sc / 64), 256, 0, stream>>>(
            aovu, slot + 3145728, ob_l, obv, nullptr, Sc, Dc, Dc);
        smaddln_k<<<MR, 256, 0, stream>>>(hb, obv, ln1g + l * Dc, ln1b + l * Dc);

        // FFN: w1 on 256^2 8-phase (grid 256); w2 on 256x128 8-phase (grid 8x32 = 256)
        mgemm256_k<<<dim3(DFFc / 256, MR / 256), 512, 0, stream>>>(
            hb, slot + 4194304, b1_l, midu, MR, DFFc, Dc, 1);
        mgemm256x128_k<<<dim3(Dc / 128, MR / 256), 512, 0, stream>>>(
            midu, slot + 6291456, b2_l, nullptr, 0, nullptr, ffu, 1, MR, Dc, DFFc, 0);
        add_ln_k<<<MR, 256, 0, stream>>>(hb, ffu, ln2g + l * Dc, ln2b + l * Dc);
    }

    // ---- head: out = h @ Wc + bc, Wc = fc1_w·fc2_w^5·fc3_w (fc2 affine, applied 5x) ----
    gemm_k<0, false, false><<<dim3(4, 4), 256, 0, stream>>>(
        fc2w, fc2w, nullptr, W2, nullptr, HIDc, HIDc, HIDc, 1.f);
    gemm_k<0, false, false><<<dim3(4, 4), 256, 0, stream>>>(
        W2, W2, nullptr, W4, nullptr, HIDc, HIDc, HIDc, 1.f);
    gemm_k<0, false, false><<<dim3(4, 4), 256, 0, stream>>>(
        W4, fc2w, nullptr, W5, nullptr, HIDc, HIDc, HIDc, 1.f);
    gemm_k<0, false, false><<<dim3(4, 16), 256, 0, stream>>>(
        fc1w, W5, nullptr, C1, nullptr, Dc, HIDc, HIDc, 1.f);
    gemm_k<0, false, false><<<dim3(4, 16), 256, 0, stream>>>(
        C1, fc3w, nullptr, Wc, nullptr, Dc, HIDc, HIDc, 1.f);
    biaschain_k<<<1, 256, 0, stream>>>(fc1b, fc2w, fc2b, fc3w, fc3b, bcv);
    transp_k<<<dim3(HIDc / 64, Dc / 64), 256, 0, stream>>>(Wc, Wt, Dc, HIDc, 1.f);
    mgemm64_k<0><<<dim3(HIDc / 64, MR / 64), 256, 0, stream>>>(
        hb, Wt, bcv, (float*)d_out, nullptr, MR, HIDc, Dc);
}

// Round 15
// 1197.098 us; speedup vs baseline: 1.0709x; 1.0709x over previous
//
#include <hip/hip_runtime.h>
#include <hip/hip_bf16.h>

using bf16 = __hip_bfloat16;
typedef __attribute__((ext_vector_type(8))) short short8v;
typedef __attribute__((ext_vector_type(4))) float floatx4;

// Problem dims
constexpr int Bc = 16, Sc = 512, INc = 512, OUTc = 256;
constexpr int Dc = 1024, Hc = 16, Lc = 6, DFFc = 2048, HIDc = 256;
constexpr float SCALEc = 0.125f; // HD^-0.5
constexpr int QKVS = 3072;       // fused qkv row stride
constexpr size_t LSLOT = 8388608; // ushorts per layer weight slot (16 MiB): qkvo|w1|w2

__device__ inline ushort f2b(float f) { // fp32 -> bf16 RNE
    union { float f; unsigned u; } v; v.f = f;
    unsigned r = (v.u + 0x7FFF + ((v.u >> 16) & 1)) >> 16;
    return (ushort)r;
}
__device__ inline float b2f(ushort b) {
    union { unsigned u; float f; } v; v.u = ((unsigned)b) << 16;
    return v.f;
}
__device__ inline float ldf(const float* p) { return *p; }
__device__ inline float ldf(const ushort* p) { return b2f(*p); }

// async global->LDS, 16 B per lane. LDS dest is wave-uniform base + lane*16 (m104).
__device__ inline void gll16(const ushort* g, ushort* l) {
    __builtin_amdgcn_global_load_lds(
        (const __attribute__((address_space(1))) unsigned int*)g,
        (__attribute__((address_space(3))) unsigned int*)l, 16, 0, 0);
}

// ---------------- block reductions (256 threads, wave64) ----------------
__device__ inline float blockSum256(float v) {
    __shared__ float tmp[4];
#pragma unroll
    for (int o = 32; o > 0; o >>= 1) v += __shfl_xor(v, o, 64);
    int w = threadIdx.x >> 6;
    __syncthreads();
    if ((threadIdx.x & 63) == 0) tmp[w] = v;
    __syncthreads();
    return tmp[0] + tmp[1] + tmp[2] + tmp[3];
}
__device__ inline float blockMax256(float v) {
    __shared__ float tmp[4];
#pragma unroll
    for (int o = 32; o > 0; o >>= 1) v = fmaxf(v, __shfl_xor(v, o, 64));
    int w = threadIdx.x >> 6;
    __syncthreads();
    if ((threadIdx.x & 63) == 0) tmp[w] = v;
    __syncthreads();
    return fmaxf(fmaxf(tmp[0], tmp[1]), fmaxf(tmp[2], tmp[3]));
}

// ---------------- mask flag: (sum(xm[0,:]) == 0) ----------------
__global__ __launch_bounds__(256) void mask_k(const float* __restrict__ xm, float* __restrict__ flag) {
    float s = xm[threadIdx.x] + xm[threadIdx.x + 256];
    s = blockSum256(s);
    if (threadIdx.x == 0) flag[0] = (s == 0.f) ? 1.f : 0.f;
}

// ---------------- x -> bf16 (same RNE as ld16 -> bitwise-identical downstream) --------
__global__ __launch_bounds__(256) void cvtx_k(const float* __restrict__ x, ushort* __restrict__ xb) {
    const size_t i = ((size_t)blockIdx.x * 256 + threadIdx.x) * 16;
    __align__(16) ushort o[16];
#pragma unroll
    for (int u = 0; u < 4; ++u) {
        float4 v = *(const float4*)&x[i + u * 4];
        o[u * 4 + 0] = f2b(v.x); o[u * 4 + 1] = f2b(v.y);
        o[u * 4 + 2] = f2b(v.z); o[u * 4 + 3] = f2b(v.w);
    }
    *(short8v*)&xb[i] = *(short8v*)&o[0];
    *(short8v*)&xb[i + 8] = *(short8v*)&o[8];
}

// ---------------- weight transpose + bf16 cvt: Wt[n][k] = bf16(W[k][n]*s) ----------------
__global__ __launch_bounds__(256) void transp_k(const float* __restrict__ W, ushort* __restrict__ Wt,
                                                int K, int N, float wscale) {
    __shared__ float Ls[64][65];
    const int t = threadIdx.x;
    const int n0 = blockIdx.x * 64, k0 = blockIdx.y * 64;
    const int kr = t >> 4, n4 = (t & 15) * 4;
#pragma unroll
    for (int p = 0; p < 4; ++p) {
        float4 v = *(const float4*)&W[(size_t)(k0 + kr + p * 16) * N + n0 + n4];
        Ls[kr + p * 16][n4 + 0] = v.x; Ls[kr + p * 16][n4 + 1] = v.y;
        Ls[kr + p * 16][n4 + 2] = v.z; Ls[kr + p * 16][n4 + 3] = v.w;
    }
    __syncthreads();
    const int nr = t >> 4, k4 = (t & 15) * 4;
#pragma unroll
    for (int p = 0; p < 4; ++p) {
        ushort4 o;
        o.x = f2b(Ls[k4 + 0][nr + p * 16] * wscale); o.y = f2b(Ls[k4 + 1][nr + p * 16] * wscale);
        o.z = f2b(Ls[k4 + 2][nr + p * 16] * wscale); o.w = f2b(Ls[k4 + 3][nr + p * 16] * wscale);
        *(ushort4*)&Wt[(size_t)(n0 + nr + p * 16) * K + k0 + k4] = o;
    }
}

// ---------------- batched layer-weight transpose (compact grid, ushort8 writes) ------
__global__ __launch_bounds__(256) void transpall_k(
    const float* __restrict__ qw, const float* __restrict__ kw, const float* __restrict__ vw,
    const float* __restrict__ ow, const float* __restrict__ w1, const float* __restrict__ w2,
    ushort* __restrict__ Wt, int l0, size_t lstride)
{
    const int l = l0 + blockIdx.y;
    ushort* slot = Wt + (size_t)blockIdx.y * lstride;
    const int id = blockIdx.x;
    int m, tx, ty;
    if (id < 1024)      { m = id >> 8; int r = id & 255;  tx = r & 15; ty = r >> 4; }
    else if (id < 1536) { m = 4;       int r = id - 1024; tx = r & 31; ty = r >> 5; }
    else                { m = 5;       int r = id - 1536; tx = r & 15; ty = r >> 4; }
    const float* W; ushort* dst; int K, N; float wscale = 1.f;
    switch (m) {
        case 0: W = qw + (size_t)l * Dc * Dc; K = Dc; N = Dc; dst = slot; wscale = SCALEc; break;
        case 1: W = kw + (size_t)l * Dc * Dc; K = Dc; N = Dc; dst = slot + 1048576; break;
        case 2: W = vw + (size_t)l * Dc * Dc; K = Dc; N = Dc; dst = slot + 2097152; break;
        case 3: W = ow + (size_t)l * Dc * Dc; K = Dc; N = Dc; dst = slot + 3145728; break;
        case 4: W = w1 + (size_t)l * Dc * DFFc; K = Dc; N = DFFc; dst = slot + 4194304; break;
        default: W = w2 + (size_t)l * DFFc * Dc; K = DFFc; N = Dc; dst = slot + 6291456; break;
    }
    __shared__ float Ls[64][65];
    const int t = threadIdx.x;
    const int n0 = tx * 64, k0 = ty * 64;
    const int kr = t >> 4, n4 = (t & 15) * 4;
#pragma unroll
    for (int p = 0; p < 4; ++p) {
        float4 v = *(const float4*)&W[(size_t)(k0 + kr + p * 16) * N + n0 + n4];
        Ls[kr + p * 16][n4 + 0] = v.x; Ls[kr + p * 16][n4 + 1] = v.y;
        Ls[kr + p * 16][n4 + 2] = v.z; Ls[kr + p * 16][n4 + 3] = v.w;
    }
    __syncthreads();
#pragma unroll
    for (int p = 0; p < 2; ++p) {
        const int idx = t + 256 * p;
        const int n = idx >> 3, kc = (idx & 7) * 8;
        __align__(16) ushort tmp[8];
#pragma unroll
        for (int u = 0; u < 8; ++u) tmp[u] = f2b(Ls[kc + u][n] * wscale);
        *(short8v*)&dst[(size_t)(n0 + n) * K + k0 + kc] = *(short8v*)tmp;
    }
}

// ---------------- MFMA GEMM (128x128 tile, BK=64, 4 waves, XOR-swizzled LDS) ----------
// Staging: global_load_lds width=16; linear LDS dest + inverse-swizzled global source
// chunk (rule #21) matching the swizzled ds_read. OMODE: 0=fp32, 1=bf16, 2=both.
template <int ACT, bool ADDPOS, int OMODE>
__global__ __launch_bounds__(256) void mgemm_k(
    const ushort* __restrict__ A, const ushort* __restrict__ Bt,
    const float* __restrict__ bias, const float* __restrict__ pos,
    float* __restrict__ Cf, ushort* __restrict__ Cb,
    int M, int N, int K, float scale)
{
    __shared__ __align__(16) ushort As[128 * 64];
    __shared__ __align__(16) ushort Bs[128 * 64];
    const int tid = threadIdx.x;
    const int nx = gridDim.x;
    const int nwg = nx * gridDim.y;
    int d = blockIdx.x + blockIdx.y * nx;
    if ((nwg & 7) == 0) d = (d & 7) * (nwg >> 3) + (d >> 3); // XCD swizzle, bijective
    const int m0 = (d / nx) * 128, n0 = (d % nx) * 128;
    const int lane = tid & 63, wv = tid >> 6;
    const int wm = (wv >> 1) * 64, wn = (wv & 1) * 64;
    floatx4 acc[4][4] = {};

    const int rA8 = lane >> 3, cch = lane & 7;

    for (int k0 = 0; k0 < K; k0 += 64) {
#pragma unroll
        for (int p = 0; p < 4; ++p) {
            const int r = wv * 32 + p * 8 + rA8;
            const int cs = (cch ^ (r & 7)) * 8;
            gll16(&Bt[(size_t)(n0 + r) * K + k0 + cs], &Bs[(wv * 32 + p * 8) * 64]);
            gll16(&A[(size_t)(m0 + r) * K + k0 + cs], &As[(wv * 32 + p * 8) * 64]);
        }
        __syncthreads();
#pragma unroll
        for (int s = 0; s < 2; ++s) {
            short8v af[4], bf_[4];
            const int kg = s * 32 + (lane >> 4) * 8;
#pragma unroll
            for (int f = 0; f < 4; ++f) {
                const int ra = wm + f * 16 + (lane & 15);
                af[f] = *(const short8v*)&As[ra * 64 + (kg ^ ((ra & 7) * 8))];
                const int rb = wn + f * 16 + (lane & 15);
                bf_[f] = *(const short8v*)&Bs[rb * 64 + (kg ^ ((rb & 7) * 8))];
            }
#pragma unroll
            for (int i = 0; i < 4; ++i)
#pragma unroll
                for (int j = 0; j < 4; ++j)
                    acc[i][j] = __builtin_amdgcn_mfma_f32_16x16x32_bf16(af[i], bf_[j], acc[i][j], 0, 0, 0);
        }
        __syncthreads();
    }

    const int cc = lane & 15, rr4 = (lane >> 4) * 4;
#pragma unroll
    for (int i = 0; i < 4; ++i) {
#pragma unroll
        for (int j = 0; j < 4; ++j) {
            const int col = n0 + wn + j * 16 + cc;
            const float bsv = bias[col];
#pragma unroll
            for (int q = 0; q < 4; ++q) {
                const int row = m0 + wm + i * 16 + rr4 + q;
                float v = acc[i][j][q] + bsv;
                if (ADDPOS) v += pos[(size_t)(row & (Sc - 1)) * N + col];
                v *= scale;
                if (ACT == 1) v = fmaxf(v, 0.f);
                if (OMODE == 0) Cf[(size_t)row * N + col] = v;
                else if (OMODE == 1) Cb[(size_t)row * N + col] = f2b(v);
                else { Cf[(size_t)row * N + col] = v; Cb[(size_t)row * N + col] = f2b(v); }
            }
        }
    }
}

// ---------------- 64x64-tile MFMA GEMM for small-M / grid-starved shapes ------------
template <int OMODE>
__global__ __launch_bounds__(256) void mgemm64_k(
    const ushort* __restrict__ A, const ushort* __restrict__ Bt,
    const float* __restrict__ bias,
    float* __restrict__ Cf, ushort* __restrict__ Cb,
    int M, int N, int K)
{
    __shared__ __align__(16) ushort As[64 * 64];
    __shared__ __align__(16) ushort Bs[64 * 64];
    const int tid = threadIdx.x;
    const int nx = gridDim.x;
    const int nwg = nx * gridDim.y;
    int d = blockIdx.x + blockIdx.y * nx;
    if ((nwg & 7) == 0) d = (d & 7) * (nwg >> 3) + (d >> 3); // XCD swizzle, bijective
    const int m0 = (d / nx) * 64, n0 = (d % nx) * 64;
    const int lane = tid & 63, wv = tid >> 6;
    floatx4 acc[4] = {};

    const int rA8 = lane >> 3, cch = lane & 7;

    for (int k0 = 0; k0 < K; k0 += 64) {
#pragma unroll
        for (int p = 0; p < 2; ++p) {
            const int r = wv * 16 + p * 8 + rA8;
            const int cs = (cch ^ (r & 7)) * 8;
            gll16(&A[(size_t)(m0 + r) * K + k0 + cs], &As[(wv * 16 + p * 8) * 64]);
            gll16(&Bt[(size_t)(n0 + r) * K + k0 + cs], &Bs[(wv * 16 + p * 8) * 64]);
        }
        __syncthreads();
#pragma unroll
        for (int s = 0; s < 2; ++s) {
            const int kg = s * 32 + (lane >> 4) * 8;
            const int rb = wv * 16 + (lane & 15);
            short8v bf_ = *(const short8v*)&Bs[rb * 64 + (kg ^ ((rb & 7) * 8))];
#pragma unroll
            for (int f = 0; f < 4; ++f) {
                const int ra = f * 16 + (lane & 15);
                short8v af = *(const short8v*)&As[ra * 64 + (kg ^ ((ra & 7) * 8))];
                acc[f] = __builtin_amdgcn_mfma_f32_16x16x32_bf16(af, bf_, acc[f], 0, 0, 0);
            }
        }
        __syncthreads();
    }

    const int cc = lane & 15, rr4 = (lane >> 4) * 4;
    const int col = n0 + wv * 16 + cc;
    const float bsv = bias[col];
#pragma unroll
    for (int f = 0; f < 4; ++f) {
#pragma unroll
        for (int q = 0; q < 4; ++q) {
            const int row = m0 + f * 16 + rr4 + q;
            float v = acc[f][q] + bsv;
            if (OMODE == 0) Cf[(size_t)row * N + col] = v;
            else            Cb[(size_t)row * N + col] = f2b(v);
        }
    }
}

// ---------------- 256x256 8-phase MFMA GEMM (w1: grid 256 = 1 block/CU) ----------
#define SG256(ts, g) do { \
    if ((ts) < NT) { \
        const int sb_ = (ts) & 1; \
        const int kk_ = (ts) << 6; \
        _Pragma("unroll") \
        for (int ii_ = 0; ii_ < 2; ++ii_) { \
            const int ib_ = wv * 16 + ii_ * 8; \
            if ((g) == 0 || (g) == 2) { \
                const int r0_ = (ib_ < 64 ? ib_ : ib_ + 64) + (((g) == 2) ? 64 : 0); \
                const int rr_ = r0_ + rA8; \
                gll16(A + (size_t)(m0 + rr_) * K + kk_ + ((cch ^ (rr_ & 7)) << 3), \
                      &Al[sb_][r0_ * 64]); \
            } else { \
                const int r0_ = ((ib_ >> 5) * 64) + (ib_ & 31) + (((g) == 3) ? 32 : 0); \
                const int rr_ = r0_ + rA8; \
                gll16(Bt + (size_t)(n0 + rr_) * K + kk_ + ((cch ^ (rr_ & 7)) << 3), \
                      &Bl[sb_][r0_ * 64]); \
            } \
        } \
    } } while (0)

#define LDA256(bb, fb) \
    _Pragma("unroll") for (int f_ = 0; f_ < 4; ++f_) { \
        const int ra_ = wm + ((fb) + f_) * 16 + (lane & 15); \
        const int sw_ = (ra_ & 7) * 8; \
        af[f_][0] = *(const short8v*)&Al[bb][ra_ * 64 + ((kgl) ^ sw_)]; \
        af[f_][1] = *(const short8v*)&Al[bb][ra_ * 64 + ((32 + kgl) ^ sw_)]; }

#define LDB256(bb, jb) \
    _Pragma("unroll") for (int f_ = 0; f_ < 2; ++f_) { \
        const int rb_ = wn + ((jb) + f_) * 16 + (lane & 15); \
        const int sw_ = (rb_ & 7) * 8; \
        bf_[(jb) + f_][0] = *(const short8v*)&Bl[bb][rb_ * 64 + ((kgl) ^ sw_)]; \
        bf_[(jb) + f_][1] = *(const short8v*)&Bl[bb][rb_ * 64 + ((32 + kgl) ^ sw_)]; }

#define MM256(ib, jb) \
    __builtin_amdgcn_s_setprio(1); \
    _Pragma("unroll") for (int i_ = 0; i_ < 4; ++i_) \
    _Pragma("unroll") for (int j_ = 0; j_ < 2; ++j_) \
    _Pragma("unroll") for (int s_ = 0; s_ < 2; ++s_) \
        acc[(ib) + i_][(jb) + j_] = __builtin_amdgcn_mfma_f32_16x16x32_bf16( \
            af[i_][s_], bf_[(jb) + j_][s_], acc[(ib) + i_][(jb) + j_], 0, 0, 0); \
    __builtin_amdgcn_s_setprio(0);

__global__ __launch_bounds__(512) void mgemm256_k(
    const ushort* __restrict__ A, const ushort* __restrict__ Bt,
    const float* __restrict__ bias, ushort* __restrict__ Cb,
    int M, int N, int K, int ACT)
{
    __shared__ __align__(16) ushort Al[2][256 * 64];
    __shared__ __align__(16) ushort Bl[2][256 * 64];
    const int tid = threadIdx.x;
    const int lane = tid & 63, wv = tid >> 6;
    const int nx = gridDim.x, nwg = nx * gridDim.y;
    int d = blockIdx.x + blockIdx.y * nx;
    if ((nwg & 7) == 0) d = (d & 7) * (nwg >> 3) + (d >> 3);
    const int m0 = (d / nx) * 256, n0 = (d % nx) * 256;
    const int wm = (wv >> 2) * 128, wn = (wv & 3) * 64;
    const int rA8 = lane >> 3, cch = lane & 7;
    const int kgl = (lane >> 4) * 8;
    const int NT = K >> 6;
    floatx4 acc[8][4] = {};
    short8v af[4][2], bf_[4][2];

    SG256(0, 0); SG256(0, 1); SG256(0, 2); SG256(0, 3);
    SG256(1, 0); SG256(1, 1); SG256(1, 2);
    asm volatile("s_waitcnt vmcnt(6)" ::: "memory");
    __builtin_amdgcn_s_barrier();

    for (int t = 0; t < NT; ++t) {
        const int bb = t & 1;
        if (t + 1 < NT) { asm volatile("s_waitcnt vmcnt(6)" ::: "memory"); }
        else            { asm volatile("s_waitcnt vmcnt(0)" ::: "memory"); }
        LDA256(bb, 0); LDB256(bb, 0);
        SG256(t + 1, 3);
        __builtin_amdgcn_s_barrier();
        MM256(0, 0);
        __builtin_amdgcn_s_barrier();
        LDB256(bb, 2);
        SG256(t + 2, 0);
        __builtin_amdgcn_s_barrier();
        MM256(0, 2);
        __builtin_amdgcn_s_barrier();
        LDA256(bb, 4);
        SG256(t + 2, 1);
        __builtin_amdgcn_s_barrier();
        MM256(4, 0);
        __builtin_amdgcn_s_barrier();
        SG256(t + 2, 2);
        __builtin_amdgcn_s_barrier();
        MM256(4, 2);
        __builtin_amdgcn_s_barrier();
    }

    const int cc = lane & 15, rr4 = (lane >> 4) * 4;
#pragma unroll
    for (int i = 0; i < 8; ++i) {
#pragma unroll
        for (int j = 0; j < 4; ++j) {
            const int col = n0 + wn + j * 16 + cc;
            const float bsv = bias[col];
#pragma unroll
            for (int q = 0; q < 4; ++q) {
                const int row = m0 + wm + i * 16 + rr4 + q;
                float v = acc[i][j][q] + bsv;
                if (ACT) v = fmaxf(v, 0.f);
                Cb[(size_t)row * N + col] = f2b(v);
            }
        }
    }
}

// ---------------- fused attention (batch 0, bf16 qkv) ----------------
__global__ __launch_bounds__(256) void fattn_k(
    const ushort* __restrict__ qkv, ushort* __restrict__ ao, const float* __restrict__ flag)
{
    const int hh = blockIdx.y;
    const int t0 = blockIdx.x * 16;
    __shared__ __align__(16) ushort Qs[16 * 64];
    __shared__ __align__(16) ushort Ks[64 * 64];
    __shared__ float Vs[64][68];
    __shared__ float Ps[16][68];
    __shared__ float rs[4][16];
    const int tid = threadIdx.x;
    const int lane = tid & 63, wv = tid >> 6;
    const bool msk = flag[0] > 0.5f;

    if (tid < 128) {
        const int r = tid >> 3, c = tid & 7;
        short8v q = *(const short8v*)&qkv[(size_t)(t0 + r) * QKVS + hh * 64 + c * 8];
        *(short8v*)&Qs[r * 64 + ((c * 8) ^ ((r & 7) * 8))] = q;
    }
    if (tid < 64) ((float*)rs)[tid] = 0.f;

    float o[4] = {};
    const int pq = tid >> 4, pd = (tid & 15) * 4;

    for (int s0 = 0; s0 < Sc; s0 += 64) {
        __syncthreads();
        {
            const int vr = tid >> 2, vc = (tid & 3) * 16;
            const ushort* vsrc = &qkv[(size_t)(s0 + vr) * QKVS + 2048 + hh * 64 + vc];
            short8v v0 = *(const short8v*)vsrc, v1 = *(const short8v*)(vsrc + 8);
#pragma unroll
            for (int u = 0; u < 8; ++u) {
                Vs[vr][vc + u] = b2f((ushort)v0[u]);
                Vs[vr][vc + 8 + u] = b2f((ushort)v1[u]);
            }
#pragma unroll
            for (int u = 0; u < 2; ++u) {
                const int task = tid + u * 256;
                const int kr = task >> 3, kc = task & 7;
                short8v kvv = *(const short8v*)&qkv[(size_t)(s0 + kr) * QKVS + 1024 + hh * 64 + kc * 8];
                *(short8v*)&Ks[kr * 64 + ((kc * 8) ^ ((kr & 7) * 8))] = kvv;
            }
        }
        __syncthreads();
        floatx4 pacc = {};
#pragma unroll
        for (int s = 0; s < 2; ++s) {
            const int kg = s * 32 + (lane >> 4) * 8;
            const int ra = lane & 15;
            short8v aq = *(const short8v*)&Qs[ra * 64 + (kg ^ ((ra & 7) * 8))];
            const int rb = 16 * wv + (lane & 15);
            short8v bk = *(const short8v*)&Ks[rb * 64 + (kg ^ ((rb & 7) * 8))];
            pacc = __builtin_amdgcn_mfma_f32_16x16x32_bf16(aq, bk, pacc, 0, 0, 0);
        }
        const int cc = lane & 15, rr4 = (lane >> 4) * 4;
#pragma unroll
        for (int q = 0; q < 4; ++q) {
            float v = fminf(fmaxf(pacc[q], -10.f), 10.f);
            if (msk) v = -10.f;
            float e = __expf(v - 10.f);
            Ps[rr4 + q][wv * 16 + cc] = e;
            float rsum = e;
            rsum += __shfl_xor(rsum, 1, 64);
            rsum += __shfl_xor(rsum, 2, 64);
            rsum += __shfl_xor(rsum, 4, 64);
            rsum += __shfl_xor(rsum, 8, 64);
            if (cc == 0) rs[wv][rr4 + q] += rsum;
        }
        __syncthreads();
#pragma unroll 8
        for (int ss = 0; ss < 64; ++ss) {
            float p = Ps[pq][ss];
#pragma unroll
            for (int u = 0; u < 4; ++u) o[u] += p * Vs[ss][pd + u];
        }
    }
    __syncthreads();
    float inv = 1.f / (rs[0][pq] + rs[1][pq] + rs[2][pq] + rs[3][pq]);
#pragma unroll
    for (int u = 0; u < 4; ++u)
        ao[(size_t)(t0 + pq) * Dc + hh * 64 + pd + u] = f2b(o[u] * inv);
}

// ---------------- fp32 VALU GEMM (head composition): C = A@W ----------------
template <int ACT, bool OUT_BF16, bool HASB>
__global__ __launch_bounds__(256) void gemm_k(
    const float* __restrict__ A, const float* __restrict__ W,
    const float* __restrict__ bias,
    float* __restrict__ Cf, bf16* __restrict__ Cb,
    int M, int N, int K, float scale)
{
    __shared__ float As[16][68];
    __shared__ float Ws[16][68];
    const int tid = threadIdx.x;
    const int m0 = blockIdx.y * 64, n0 = blockIdx.x * 64;
    const int ty = tid >> 4, tx = tid & 15;
    float c[4][4] = {};

    const int ka = tid & 15, mb = tid >> 4;
    const int nw = tid & 63, kb = tid >> 6;

    for (int k0 = 0; k0 < K; k0 += 16) {
#pragma unroll
        for (int j = 0; j < 4; ++j) {
            int m = mb + 16 * j;
            As[ka][m] = A[(size_t)(m0 + m) * K + k0 + ka];
        }
#pragma unroll
        for (int j = 0; j < 4; ++j) {
            int k = kb + 4 * j;
            Ws[k][nw] = W[(size_t)(k0 + k) * N + n0 + nw];
        }
        __syncthreads();
#pragma unroll
        for (int k = 0; k < 16; ++k) {
            float4 av = *(const float4*)&As[k][ty * 4];
            float4 wv = *(const float4*)&Ws[k][tx * 4];
            float a[4] = {av.x, av.y, av.z, av.w};
            float w[4] = {wv.x, wv.y, wv.z, wv.w};
#pragma unroll
            for (int i = 0; i < 4; ++i)
#pragma unroll
                for (int j = 0; j < 4; ++j) c[i][j] += a[i] * w[j];
        }
        __syncthreads();
    }

#pragma unroll
    for (int i = 0; i < 4; ++i) {
        int m = m0 + ty * 4 + i;
#pragma unroll
        for (int j = 0; j < 4; ++j) {
            int n = n0 + tx * 4 + j;
            float v = c[i][j] + (HASB ? bias[n] : 0.f);
            v *= scale;
            if (ACT == 1) v = fmaxf(v, 0.f);
            if (OUT_BF16) Cb[(size_t)m * N + n] = __float2bfloat16(v);
            else          Cf[(size_t)m * N + n] = v;
        }
    }
}

// ---------------- fused head bias chain ----------------
__global__ __launch_bounds__(256) void biaschain_k(
    const float* __restrict__ fc1b, const float* __restrict__ fc2w, const float* __restrict__ fc2b,
    const float* __restrict__ fc3w, const float* __restrict__ fc3b, float* __restrict__ bc)
{
    __shared__ float vs[256];
    const int t = threadIdx.x;
    float v = fc1b[t];
    for (int r = 0; r < 5; ++r) {
        vs[t] = v; __syncthreads();
        float s = fc2b[t];
#pragma unroll 8
        for (int k = 0; k < 256; ++k) s += vs[k] * fc2w[k * 256 + t];
        v = s; __syncthreads();
    }
    vs[t] = v; __syncthreads();
    float s = fc3b[t];
#pragma unroll 8
    for (int k = 0; k < 256; ++k) s += vs[k] * fc3w[k * 256 + t];
    bc[t] = s;
}

// ---------------- qkv bias concat for ALL layers (q-part pre-scaled) ----------------
__global__ __launch_bounds__(256) void qkvbiasall_k(
    const float* __restrict__ qb, const float* __restrict__ kb, const float* __restrict__ vb,
    float* __restrict__ o)
{
    int i = blockIdx.x * 256 + threadIdx.x; // grid 72 -> 6*3072
    int l = i / QKVS, j = i - l * QKVS;
    float v = (j < 1024) ? qb[l * Dc + j] * SCALEc
            : (j < 2048) ? kb[l * Dc + j - 1024] : vb[l * Dc + j - 2048];
    o[i] = v;
}

// ---------------- fused: hb = LN(hb + softmax(clip(obv_row))) (bcast over batch) ------
__global__ __launch_bounds__(256) void smaddln_k(
    ushort* __restrict__ hb, const float* __restrict__ obv,
    const float* __restrict__ g, const float* __restrict__ b)
{
    const int row = blockIdx.x;
    const float* op = obv + (size_t)(row & (Sc - 1)) * Dc;
    ushort* hp = hb + (size_t)row * Dc;
    const int c0 = threadIdx.x * 4;
    float4 ov = *(const float4*)&op[c0];
    float r[4] = {ov.x, ov.y, ov.z, ov.w};
    float mx = -1e30f;
#pragma unroll
    for (int j = 0; j < 4; ++j) { r[j] = fminf(fmaxf(r[j], -10.f), 10.f); mx = fmaxf(mx, r[j]); }
    mx = blockMax256(mx);
    float s = 0.f;
#pragma unroll
    for (int j = 0; j < 4; ++j) { r[j] = __expf(r[j] - mx); s += r[j]; }
    s = blockSum256(s);
    float sinv = 1.f / s;
    ushort4 hv = *(const ushort4*)&hp[c0];
    float x[4] = {b2f(hv.x), b2f(hv.y), b2f(hv.z), b2f(hv.w)};
    float ssum = 0.f;
#pragma unroll
    for (int j = 0; j < 4; ++j) { x[j] += r[j] * sinv; ssum += x[j]; }
    float mean = blockSum256(ssum) * (1.f / (float)Dc);
    float vsum = 0.f;
#pragma unroll
    for (int j = 0; j < 4; ++j) { float d_ = x[j] - mean; vsum += d_ * d_; }
    float var = blockSum256(vsum) * (1.f / (float)Dc);
    float inv = rsqrtf(var + 1e-5f);
    float4 gv = *(const float4*)&g[c0];
    float4 bv = *(const float4*)&b[c0];
    ushort4 o4;
    o4.x = f2b((x[0] - mean) * inv * gv.x + bv.x);
    o4.y = f2b((x[1] - mean) * inv * gv.y + bv.y);
    o4.z = f2b((x[2] - mean) * inv * gv.z + bv.z);
    o4.w = f2b((x[3] - mean) * inv * gv.w + bv.w);
    *(ushort4*)&hp[c0] = o4;
}

// ---------------- hb = bf16(LN(hb + add)) ----------------
__global__ __launch_bounds__(256) void add_ln_k(
    ushort* __restrict__ hb, const ushort* __restrict__ add,
    const float* __restrict__ g, const float* __restrict__ b)
{
    const int row = blockIdx.x;
    const ushort* ap = add + (size_t)row * Dc;
    ushort* hp = hb + (size_t)row * Dc;
    const int c0 = threadIdx.x * 4;
    ushort4 hv = *(const ushort4*)&hp[c0];
    float x[4] = {b2f(hv.x), b2f(hv.y), b2f(hv.z), b2f(hv.w)};
#pragma unroll
    for (int j = 0; j < 4; ++j) x[j] += ldf(&ap[c0 + j]);
    float s = x[0] + x[1] + x[2] + x[3];
    float mean = blockSum256(s) * (1.f / (float)Dc);
    float vsum = 0.f;
#pragma unroll
    for (int j = 0; j < 4; ++j) { float d = x[j] - mean; vsum += d * d; }
    float var = blockSum256(vsum) * (1.f / (float)Dc);
    float inv = rsqrtf(var + 1e-5f);
    float4 gv = *(const float4*)&g[c0];
    float4 bv = *(const float4*)&b[c0];
    ushort4 ov;
    ov.x = f2b((x[0] - mean) * inv * gv.x + bv.x);
    ov.y = f2b((x[1] - mean) * inv * gv.y + bv.y);
    ov.z = f2b((x[2] - mean) * inv * gv.z + bv.z);
    ov.w = f2b((x[3] - mean) * inv * gv.w + bv.w);
    *(ushort4*)&hp[c0] = ov;
}

// ---------------- launch ----------------
extern "C" void kernel_launch(void* const* d_in, const int* in_sizes, int n_in,
                              void* d_out, int out_size, void* d_ws, size_t ws_size,
                              hipStream_t stream)
{
    const float* x      = (const float*)d_in[0];
    const float* xm     = (const float*)d_in[1];
    // d_in[2] vecSelector: assert-only, unused
    const float* proj_w = (const float*)d_in[3];
    const float* proj_b = (const float*)d_in[4];
    const float* pos    = (const float*)d_in[5];
    const float* qw     = (const float*)d_in[6];
    const float* qb     = (const float*)d_in[7];
    const float* kw     = (const float*)d_in[8];
    const float* kb     = (const float*)d_in[9];
    const float* vw     = (const float*)d_in[10];
    const float* vb     = (const float*)d_in[11];
    const float* ow     = (const float*)d_in[12];
    const float* obias  = (const float*)d_in[13];
    const float* ln1g   = (const float*)d_in[14];
    const float* ln1b   = (const float*)d_in[15];
    const float* ln2g   = (const float*)d_in[16];
    const float* ln2b   = (const float*)d_in[17];
    const float* w1     = (const float*)d_in[18];
    const float* b1     = (const float*)d_in[19];
    const float* w2     = (const float*)d_in[20];
    const float* b2     = (const float*)d_in[21];
    const float* fc1w   = (const float*)d_in[22];
    const float* fc1b   = (const float*)d_in[23];
    const float* fc2w   = (const float*)d_in[24];
    const float* fc2b   = (const float*)d_in[25];
    const float* fc3w   = (const float*)d_in[26];
    const float* fc3b   = (const float*)d_in[27];

    float* ws = (float*)d_ws;
    const size_t HSZ = (size_t)Bc * Sc * Dc; // 8,388,608 floats
    ushort* hb  = (ushort*)ws;
    ushort* ffu = (ushort*)(ws + HSZ / 2);
    float*  rgA = ws + HSZ;
    float*  meta = ws + 2 * HSZ;
    float*  flag = meta;
    float*  qkvball = meta + 256;
    ushort* Wt = (ushort*)(ws + 2 * HSZ + 262144);

    const bool big = ws_size >= (size_t)163 * 1024 * 1024;
    const size_t lstride = big ? LSLOT : 0;
    ushort* projWt = big ? Wt + (size_t)6 * LSLOT : Wt;

    ushort* qkvfu = (ushort*)rgA;
    ushort* aovu  = (ushort*)(rgA + 786432);
    float*  obv   = rgA + 1048576;
    ushort* midu  = (ushort*)rgA;
    ushort* xb    = (ushort*)rgA;  // proj phase only (dead before layer 0's attn temps)
    float* W2  = rgA;
    float* W4  = rgA + 65536;
    float* W5  = rgA + 131072;
    float* C1  = rgA + 196608;
    float* Wc  = rgA + 458752;
    float* bcv = rgA + 720896;

    const int MR = Bc * Sc; // 8192

    mask_k<<<1, 256, 0, stream>>>(xm, flag);
    qkvbiasall_k<<<72, 256, 0, stream>>>(qb, kb, vb, qkvball);
    if (big)
        transpall_k<<<dim3(2048, 6), 256, 0, stream>>>(qw, kw, vw, ow, w1, w2, Wt, 0, lstride);

    // hb = bf16(x @ proj_w + proj_b + pos): x -> bf16 first, then gll A-path
    cvtx_k<<<(MR * INc) / (256 * 16), 256, 0, stream>>>(x, xb);
    transp_k<<<dim3(Dc / 64, INc / 64), 256, 0, stream>>>(proj_w, projWt, INc, Dc, 1.f);
    mgemm_k<0, true, 1><<<dim3(Dc / 128, MR / 128), 256, 0, stream>>>(
        xb, projWt, proj_b, pos, nullptr, hb, MR, Dc, INc, 1.f);

    for (int l = 0; l < Lc; ++l) {
        ushort* slot = Wt + (size_t)(big ? l : 0) * LSLOT;
        const float* ob_l = obias + l * Dc;
        const float* b1_l = b1 + l * DFFc;
        const float* b2_l = b2 + l * Dc;

        if (!big)
            transpall_k<<<dim3(2048, 1), 256, 0, stream>>>(qw, kw, vw, ow, w1, w2, Wt, l, 0);

        // attention: batch 0 only (sa = ao[0] is all that survives)
        mgemm64_k<1><<<dim3(QKVS / 64, Sc / 64), 256, 0, stream>>>(
            hb, slot, qkvball + l * QKVS, nullptr, qkvfu, Sc, QKVS, Dc);
        fattn_k<<<dim3(Sc / 16, Hc), 256, 0, stream>>>(qkvfu, aovu, flag);
        mgemm64_k<0><<<dim3(Dc / 64, Sc / 64), 256, 0, stream>>>(
            aovu, slot + 3145728, ob_l, obv, nullptr, Sc, Dc, Dc);
        smaddln_k<<<MR, 256, 0, stream>>>(hb, obv, ln1g + l * Dc, ln1b + l * Dc);

        // FFN: w1 on 256^2 8-phase (grid 256 = 1 block/CU); w2 on proven 128^2
        mgemm256_k<<<dim3(DFFc / 256, MR / 256), 512, 0, stream>>>(
            hb, slot + 4194304, b1_l, midu, MR, DFFc, Dc, 1);
        mgemm_k<0, false, 1><<<dim3(Dc / 128, MR / 128), 256, 0, stream>>>(
            midu, slot + 6291456, b2_l, nullptr, nullptr, ffu, MR, Dc, DFFc, 1.f);
        add_ln_k<<<MR, 256, 0, stream>>>(hb, ffu, ln2g + l * Dc, ln2b + l * Dc);
    }

    // ---- head: out = h @ Wc + bc, Wc = fc1_w·fc2_w^5·fc3_w (fc2 affine, applied 5x) ----
    gemm_k<0, false, false><<<dim3(4, 4), 256, 0, stream>>>(
        fc2w, fc2w, nullptr, W2, nullptr, HIDc, HIDc, HIDc, 1.f);
    gemm_k<0, false, false><<<dim3(4, 4), 256, 0, stream>>>(
        W2, W2, nullptr, W4, nullptr, HIDc, HIDc, HIDc, 1.f);
    gemm_k<0, false, false><<<dim3(4, 4), 256, 0, stream>>>(
        W4, fc2w, nullptr, W5, nullptr, HIDc, HIDc, HIDc, 1.f);
    gemm_k<0, false, false><<<dim3(4, 16), 256, 0, stream>>>(
        fc1w, W5, nullptr, C1, nullptr, Dc, HIDc, HIDc, 1.f);
    gemm_k<0, false, false><<<dim3(4, 16), 256, 0, stream>>>(
        C1, fc3w, nullptr, Wc, nullptr, Dc, HIDc, HIDc, 1.f);
    biaschain_k<<<1, 256, 0, stream>>>(fc1b, fc2w, fc2b, fc3w, fc3b, bcv);
    transp_k<<<dim3(HIDc / 64, Dc / 64), 256, 0, stream>>>(Wc, Wt, Dc, HIDc, 1.f);
    mgemm64_k<0><<<dim3(HIDc / 64, MR / 64), 256, 0, stream>>>(
        hb, Wt, bcv, (float*)d_out, nullptr, MR, HIDc, Dc);
}